// Round 2
// baseline (319.554 us; speedup 1.0000x reference)
//
#include <hip/hip_runtime.h>
#include <hip/hip_bf16.h>

// FlashSVDFFN: out = (gelu((x@U1)@V1 + b1)@U2)@V2 + b2
// x:[16384,1024] U1:[1024,256] V1:[256,4096] b1:[4096] U2:[4096,256] V2:[256,1024] b2:[1024]
// Fully fused, BM=32 rows/block, grid 512 (2 blocks/CU), 8 waves/block (4/SIMD).

typedef __attribute__((ext_vector_type(8))) short bfrag8;     // 8 bf16 = one A/B fragment
typedef __attribute__((ext_vector_type(4))) float fx4;        // C/D fragment
typedef __attribute__((ext_vector_type(4))) unsigned short usx4;

#define D_MODEL 1024
#define D_FF    4096
#define RANK    256
#define NROWS   16384
#define BM      32          // rows per block
#define PSTR    264         // P/H LDS row stride (256+8) in bf16
#define XSTR    136         // xs row stride (128+8) in bf16

__device__ __forceinline__ unsigned short f2b(float f) {
  union { float f; unsigned u; } v; v.f = f;
  unsigned r = v.u + 0x7FFFu + ((v.u >> 16) & 1u);   // RTNE
  return (unsigned short)(r >> 16);
}

__device__ __forceinline__ float gelu_tanh(float x) {
  float x2 = x * x;
  float y  = 0.7978845608028654f * __builtin_fmaf(0.044715f * x2, x, x);
  float ay = __builtin_fabsf(y);
  float e  = __expf(-2.0f * ay);
  float t  = (1.0f - e) * __builtin_amdgcn_rcpf(1.0f + e);   // tanh(|y|)
  t = __builtin_copysignf(t, y);
  return 0.5f * x * (1.0f + t);
}

// out[c][r] = bf16(in[r][c]); in is R x C row-major. 256 threads, 32x32 tiles.
__global__ void tconv(const float* __restrict__ in, unsigned short* __restrict__ out,
                      int R, int C) {
  __shared__ float t[32][33];
  int c0 = blockIdx.x * 32, r0 = blockIdx.y * 32;
  int tx = threadIdx.x & 31, ty = threadIdx.x >> 5;   // ty 0..7
#pragma unroll
  for (int i = 0; i < 32; i += 8)
    t[ty + i][tx] = in[(size_t)(r0 + ty + i) * C + c0 + tx];
  __syncthreads();
#pragma unroll
  for (int i = 0; i < 32; i += 8)
    out[(size_t)(c0 + ty + i) * R + r0 + tx] = f2b(t[tx][ty + i]);
}

__global__ __launch_bounds__(512, 4) void ffn_fused(
    const float* __restrict__ x,
    const unsigned short* __restrict__ u1t,   // [RANK][D_MODEL]  = U1^T
    const unsigned short* __restrict__ v1t,   // [D_FF][RANK]     = V1^T
    const float* __restrict__ b1,
    const unsigned short* __restrict__ u2t,   // [RANK][D_FF]     = U2^T
    const unsigned short* __restrict__ v2t,   // [D_MODEL][RANK]  = V2^T
    const float* __restrict__ b2,
    float* __restrict__ out)
{
  __shared__ unsigned short P_lds[BM * PSTR];   // P then Q, [32][256] (+8 pad)
  __shared__ unsigned short h_lds[BM * PSTR];   // H tile   [32][256] (+8 pad)
  __shared__ unsigned short xs[BM * XSTR];      // x tile   [32][128] (+8 pad)

  const int tid  = threadIdx.x;
  const int w    = tid >> 6;        // wave 0..7 (N-split: cols w*32..w*32+31)
  const int lane = tid & 63;
  const int lo   = lane & 15;       // frag row/col within 16
  const int hi   = lane >> 4;       // k-group: k = hi*8 + j
  const size_t gr0 = (size_t)blockIdx.x * BM;

  // ---------------- stage 1: P[32][256] = bf16(x) @ U1 ----------------
  fx4 pacc[2][2];
#pragma unroll
  for (int mt = 0; mt < 2; ++mt)
#pragma unroll
    for (int nt = 0; nt < 2; ++nt) pacc[mt][nt] = fx4{0.f, 0.f, 0.f, 0.f};

  for (int d0 = 0; d0 < D_MODEL; d0 += 128) {
    __syncthreads();
#pragma unroll
    for (int it = 0; it < 2; ++it) {            // stage+convert 32x128 f32 tile
      int idx = it * 512 + tid;
      int r = idx >> 5;                          // 32 fx4 per row
      int c = (idx & 31) << 2;
      fx4 v = *(const fx4*)(x + (gr0 + r) * D_MODEL + d0 + c);
      usx4 bv;
      bv[0] = f2b(v[0]); bv[1] = f2b(v[1]); bv[2] = f2b(v[2]); bv[3] = f2b(v[3]);
      *(usx4*)(xs + r * XSTR + c) = bv;
    }
    __syncthreads();
#pragma unroll
    for (int ks = 0; ks < 128; ks += 32) {
      bfrag8 a[2], b[2];
#pragma unroll
      for (int mt = 0; mt < 2; ++mt)
        a[mt] = *(const bfrag8*)(xs + (16 * mt + lo) * XSTR + ks + hi * 8);
#pragma unroll
      for (int nt = 0; nt < 2; ++nt)
        b[nt] = *(const bfrag8*)(u1t + (size_t)(w * 32 + nt * 16 + lo) * D_MODEL + d0 + ks + hi * 8);
#pragma unroll
      for (int mt = 0; mt < 2; ++mt)
#pragma unroll
        for (int nt = 0; nt < 2; ++nt)
          pacc[mt][nt] = __builtin_amdgcn_mfma_f32_16x16x32_bf16(a[mt], b[nt], pacc[mt][nt], 0, 0, 0);
    }
  }

  // P -> LDS as bf16.  D layout: col=lo, row=4*hi+reg (m89/m91-verified).
  __syncthreads();
#pragma unroll
  for (int mt = 0; mt < 2; ++mt)
#pragma unroll
    for (int nt = 0; nt < 2; ++nt)
#pragma unroll
      for (int r = 0; r < 4; ++r)
        P_lds[(16 * mt + 4 * hi + r) * PSTR + w * 32 + nt * 16 + lo] = f2b(pacc[mt][nt][r]);
  __syncthreads();

  // ---------------- stage 2: flash over D_FF ----------------
  fx4 qacc[2][2];
#pragma unroll
  for (int mt = 0; mt < 2; ++mt)
#pragma unroll
    for (int nt = 0; nt < 2; ++nt) qacc[mt][nt] = fx4{0.f, 0.f, 0.f, 0.f};

  for (int f0 = 0; f0 < D_FF; f0 += 256) {
    // H-GEMM: H[32][256] = P @ V1[:, f0:f0+256], K=RANK
    fx4 hacc[2][2];
#pragma unroll
    for (int mt = 0; mt < 2; ++mt)
#pragma unroll
      for (int nt = 0; nt < 2; ++nt) hacc[mt][nt] = fx4{0.f, 0.f, 0.f, 0.f};

    for (int ks = 0; ks < RANK; ks += 32) {
      bfrag8 a[2], b[2];
#pragma unroll
      for (int mt = 0; mt < 2; ++mt)
        a[mt] = *(const bfrag8*)(P_lds + (16 * mt + lo) * PSTR + ks + hi * 8);
#pragma unroll
      for (int nt = 0; nt < 2; ++nt)
        b[nt] = *(const bfrag8*)(v1t + (size_t)(f0 + w * 32 + nt * 16 + lo) * RANK + ks + hi * 8);
#pragma unroll
      for (int mt = 0; mt < 2; ++mt)
#pragma unroll
        for (int nt = 0; nt < 2; ++nt)
          hacc[mt][nt] = __builtin_amdgcn_mfma_f32_16x16x32_bf16(a[mt], b[nt], hacc[mt][nt], 0, 0, 0);
    }

    __syncthreads();   // prev Q-GEMM done reading h_lds
#pragma unroll
    for (int nt = 0; nt < 2; ++nt) {
      float bias = b1[f0 + w * 32 + nt * 16 + lo];
#pragma unroll
      for (int mt = 0; mt < 2; ++mt)
#pragma unroll
        for (int r = 0; r < 4; ++r) {
          float hv = gelu_tanh(hacc[mt][nt][r] + bias);
          h_lds[(16 * mt + 4 * hi + r) * PSTR + w * 32 + nt * 16 + lo] = f2b(hv);
        }
    }
    __syncthreads();

    // Q-GEMM: Q[32][256] += H @ U2[f0:f0+256, :], K=256
    for (int ks = 0; ks < 256; ks += 32) {
      bfrag8 a[2], b[2];
#pragma unroll
      for (int mt = 0; mt < 2; ++mt)
        a[mt] = *(const bfrag8*)(h_lds + (16 * mt + lo) * PSTR + ks + hi * 8);
#pragma unroll
      for (int nt = 0; nt < 2; ++nt)
        b[nt] = *(const bfrag8*)(u2t + (size_t)(w * 32 + nt * 16 + lo) * D_FF + f0 + ks + hi * 8);
#pragma unroll
      for (int mt = 0; mt < 2; ++mt)
#pragma unroll
        for (int nt = 0; nt < 2; ++nt)
          qacc[mt][nt] = __builtin_amdgcn_mfma_f32_16x16x32_bf16(a[mt], b[nt], qacc[mt][nt], 0, 0, 0);
    }
  }

  // ---------------- stage 3: out = Q @ V2 + b2 ----------------
  __syncthreads();   // last H-GEMM readers of P_lds done
#pragma unroll
  for (int mt = 0; mt < 2; ++mt)
#pragma unroll
    for (int nt = 0; nt < 2; ++nt)
#pragma unroll
      for (int r = 0; r < 4; ++r)
        P_lds[(16 * mt + 4 * hi + r) * PSTR + w * 32 + nt * 16 + lo] = f2b(qacc[mt][nt][r]);
  __syncthreads();

  for (int n0 = 0; n0 < D_MODEL; n0 += 256) {
    fx4 oacc[2][2];
#pragma unroll
    for (int mt = 0; mt < 2; ++mt)
#pragma unroll
      for (int nt = 0; nt < 2; ++nt) oacc[mt][nt] = fx4{0.f, 0.f, 0.f, 0.f};

    for (int ks = 0; ks < RANK; ks += 32) {
      bfrag8 a[2], b[2];
#pragma unroll
      for (int mt = 0; mt < 2; ++mt)
        a[mt] = *(const bfrag8*)(P_lds + (16 * mt + lo) * PSTR + ks + hi * 8);
#pragma unroll
      for (int nt = 0; nt < 2; ++nt)
        b[nt] = *(const bfrag8*)(v2t + (size_t)(n0 + w * 32 + nt * 16 + lo) * RANK + ks + hi * 8);
#pragma unroll
      for (int mt = 0; mt < 2; ++mt)
#pragma unroll
        for (int nt = 0; nt < 2; ++nt)
          oacc[mt][nt] = __builtin_amdgcn_mfma_f32_16x16x32_bf16(a[mt], b[nt], oacc[mt][nt], 0, 0, 0);
    }

#pragma unroll
    for (int nt = 0; nt < 2; ++nt) {
      int col = n0 + w * 32 + nt * 16 + lo;
      float bias = b2[col];
#pragma unroll
      for (int mt = 0; mt < 2; ++mt)
#pragma unroll
        for (int r = 0; r < 4; ++r)
          out[(gr0 + 16 * mt + 4 * hi + r) * D_MODEL + col] = oacc[mt][nt][r] + bias;
    }
  }
}

extern "C" void kernel_launch(void* const* d_in, const int* in_sizes, int n_in,
                              void* d_out, int out_size, void* d_ws, size_t ws_size,
                              hipStream_t stream) {
  const float* x  = (const float*)d_in[0];
  const float* U1 = (const float*)d_in[1];
  const float* V1 = (const float*)d_in[2];
  const float* b1 = (const float*)d_in[3];
  const float* U2 = (const float*)d_in[4];
  const float* V2 = (const float*)d_in[5];
  const float* b2 = (const float*)d_in[6];
  float* out = (float*)d_out;

  unsigned short* ws = (unsigned short*)d_ws;
  unsigned short* u1t = ws;                                   // [256][1024]  512KB
  unsigned short* v1t = u1t + (size_t)RANK * D_MODEL;         // [4096][256]  2MB
  unsigned short* u2t = v1t + (size_t)D_FF * RANK;            // [256][4096]  2MB
  unsigned short* v2t = u2t + (size_t)RANK * D_FF;            // [1024][256]  512KB

  // weight transpose + bf16 convert (repeated every launch: deterministic)
  tconv<<<dim3(RANK / 32, D_MODEL / 32), 256, 0, stream>>>(U1, u1t, D_MODEL, RANK);
  tconv<<<dim3(D_FF / 32, RANK / 32),   256, 0, stream>>>(V1, v1t, RANK, D_FF);
  tconv<<<dim3(RANK / 32, D_FF / 32),   256, 0, stream>>>(U2, u2t, D_FF, RANK);
  tconv<<<dim3(D_MODEL / 32, RANK / 32),256, 0, stream>>>(V2, v2t, RANK, D_MODEL);

  ffn_fused<<<NROWS / BM, 512, 0, stream>>>(x, u1t, v1t, b1, u2t, v2t, b2, out);
}

// Round 3
// 237.518 us; speedup vs baseline: 1.3454x; 1.3454x over previous
//
#include <hip/hip_runtime.h>
#include <hip/hip_bf16.h>

// FlashSVDFFN: out = (gelu((x@U1)@V1 + b1)@U2)@V2 + b2
// Split: pgemm (P = bf16(x)@U1) -> hqgemm (partial Q over f-halves, fused
// H-GEMM + gelu + Q-GEMM, never materializing H) -> ogemm (sum partials @ V2 + b2).

typedef __attribute__((ext_vector_type(8))) short bfrag8;     // 8 bf16 fragment
typedef __attribute__((ext_vector_type(4))) float fx4;
typedef __attribute__((ext_vector_type(4))) unsigned short usx4;

#define D_MODEL 1024
#define D_FF    4096
#define RANK    256
#define NROWS   16384
#define PSTR    264         // [.][256] LDS row stride (+8 pad), 528B = 16B-multiple
#define XSTR    136         // [.][128] LDS row stride (+8 pad), 272B = 16B-multiple

__device__ __forceinline__ unsigned short f2b(float f) {
  union { float f; unsigned u; } v; v.f = f;
  unsigned r = v.u + 0x7FFFu + ((v.u >> 16) & 1u);   // RTNE
  return (unsigned short)(r >> 16);
}

__device__ __forceinline__ float gelu_tanh(float x) {
  float x2 = x * x;
  float y  = 0.7978845608028654f * __builtin_fmaf(0.044715f * x2, x, x);
  float ay = __builtin_fabsf(y);
  float e  = __expf(-2.0f * ay);
  float t  = (1.0f - e) * __builtin_amdgcn_rcpf(1.0f + e);   // tanh(|y|)
  t = __builtin_copysignf(t, y);
  return 0.5f * x * (1.0f + t);
}

// out[c][r] = bf16(in[r][c]); in is R x C row-major. 256 threads, 32x32 tiles.
__global__ void tconv(const float* __restrict__ in, unsigned short* __restrict__ out,
                      int R, int C) {
  __shared__ float t[32][33];
  int c0 = blockIdx.x * 32, r0 = blockIdx.y * 32;
  int tx = threadIdx.x & 31, ty = threadIdx.x >> 5;
#pragma unroll
  for (int i = 0; i < 32; i += 8)
    t[ty + i][tx] = in[(size_t)(r0 + ty + i) * C + c0 + tx];
  __syncthreads();
#pragma unroll
  for (int i = 0; i < 32; i += 8)
    out[(size_t)(c0 + ty + i) * R + r0 + tx] = f2b(t[tx][ty + i]);
}

// ---------------- P = bf16(x) @ U1 : [16384][256] bf16 ----------------
// BM=32, 256 thr (4 waves, each 32x64 = 2x4 frags), grid 512.
__global__ __launch_bounds__(256, 4) void pgemm(
    const float* __restrict__ x, const unsigned short* __restrict__ u1t,
    unsigned short* __restrict__ P)
{
  __shared__ unsigned short xs[32 * XSTR];
  const int tid = threadIdx.x;
  const int w = tid >> 6, lane = tid & 63, lo = lane & 15, hi = lane >> 4;
  const size_t gr0 = (size_t)blockIdx.x * 32;

  fx4 acc[2][4];
#pragma unroll
  for (int mt = 0; mt < 2; ++mt)
#pragma unroll
    for (int nt = 0; nt < 4; ++nt) acc[mt][nt] = fx4{0.f, 0.f, 0.f, 0.f};

  for (int d0 = 0; d0 < D_MODEL; d0 += 128) {
    __syncthreads();
#pragma unroll
    for (int it = 0; it < 4; ++it) {            // 32x128 f32 -> bf16 LDS
      int idx = it * 256 + tid;
      int r = idx >> 5, c = (idx & 31) << 2;
      fx4 v = *(const fx4*)(x + (gr0 + r) * D_MODEL + d0 + c);
      usx4 bv; bv[0] = f2b(v[0]); bv[1] = f2b(v[1]); bv[2] = f2b(v[2]); bv[3] = f2b(v[3]);
      *(usx4*)(xs + r * XSTR + c) = bv;
    }
    __syncthreads();
#pragma unroll
    for (int ks = 0; ks < 128; ks += 32) {
      bfrag8 a[2], b[4];
#pragma unroll
      for (int mt = 0; mt < 2; ++mt)
        a[mt] = *(const bfrag8*)(xs + (16 * mt + lo) * XSTR + ks + hi * 8);
#pragma unroll
      for (int nt = 0; nt < 4; ++nt)
        b[nt] = *(const bfrag8*)(u1t + (size_t)(w * 64 + nt * 16 + lo) * D_MODEL + d0 + ks + hi * 8);
#pragma unroll
      for (int mt = 0; mt < 2; ++mt)
#pragma unroll
        for (int nt = 0; nt < 4; ++nt)
          acc[mt][nt] = __builtin_amdgcn_mfma_f32_16x16x32_bf16(a[mt], b[nt], acc[mt][nt], 0, 0, 0);
    }
  }
#pragma unroll
  for (int mt = 0; mt < 2; ++mt)
#pragma unroll
    for (int nt = 0; nt < 4; ++nt)
#pragma unroll
      for (int r = 0; r < 4; ++r)
        P[(gr0 + 16 * mt + 4 * hi + r) * RANK + w * 64 + nt * 16 + lo] = f2b(acc[mt][nt][r]);
}

// ---- partial Q = gelu(P@V1 + b1) @ U2 over an f-half : [F][16384][256] f32 ----
// BM=64, 256 thr (4 waves, each 64x64 = 4x4 frags), grid 256*F.
__global__ __launch_bounds__(256, 2) void hqgemm(
    const unsigned short* __restrict__ P,
    const unsigned short* __restrict__ v1t,   // [D_FF][RANK]
    const float* __restrict__ b1,
    const unsigned short* __restrict__ u2t,   // [RANK][D_FF]
    float* __restrict__ qpart,                // [F][NROWS][RANK]
    int fsplit, int fspan)
{
  __shared__ unsigned short P_lds[64 * PSTR];
  __shared__ unsigned short h_lds[64 * PSTR];

  const int tid = threadIdx.x;
  const int w = tid >> 6, lane = tid & 63, lo = lane & 15, hi = lane >> 4;
  int j, rb;
  if (fsplit == 2) { j = blockIdx.x & 1; rb = blockIdx.x >> 1; }   // parity -> disjoint XCD sets
  else             { j = 0;               rb = blockIdx.x; }
  const size_t gr0 = (size_t)rb * 64;
  const int fbeg = j * fspan;

  // load P tile [64][256] bf16 -> LDS (coalesced 16B chunks)
#pragma unroll
  for (int it = 0; it < 8; ++it) {
    int idx = it * 256 + tid;
    int r = idx >> 5, c = (idx & 31) << 3;
    *(bfrag8*)(P_lds + r * PSTR + c) = *(const bfrag8*)(P + (gr0 + r) * RANK + c);
  }
  __syncthreads();

  fx4 qacc[4][4];
#pragma unroll
  for (int mt = 0; mt < 4; ++mt)
#pragma unroll
    for (int nt = 0; nt < 4; ++nt) qacc[mt][nt] = fx4{0.f, 0.f, 0.f, 0.f};

  for (int f0 = fbeg; f0 < fbeg + fspan; f0 += 256) {
    fx4 hacc[4][4];
#pragma unroll
    for (int mt = 0; mt < 4; ++mt)
#pragma unroll
      for (int nt = 0; nt < 4; ++nt) hacc[mt][nt] = fx4{0.f, 0.f, 0.f, 0.f};

#pragma unroll
    for (int ks = 0; ks < RANK; ks += 32) {
      bfrag8 a[4], b[4];
#pragma unroll
      for (int mt = 0; mt < 4; ++mt)
        a[mt] = *(const bfrag8*)(P_lds + (16 * mt + lo) * PSTR + ks + hi * 8);
#pragma unroll
      for (int nt = 0; nt < 4; ++nt)
        b[nt] = *(const bfrag8*)(v1t + (size_t)(f0 + w * 64 + nt * 16 + lo) * RANK + ks + hi * 8);
#pragma unroll
      for (int mt = 0; mt < 4; ++mt)
#pragma unroll
        for (int nt = 0; nt < 4; ++nt)
          hacc[mt][nt] = __builtin_amdgcn_mfma_f32_16x16x32_bf16(a[mt], b[nt], hacc[mt][nt], 0, 0, 0);
    }

    __syncthreads();   // prev Q-GEMM done reading h_lds
#pragma unroll
    for (int nt = 0; nt < 4; ++nt) {
      float bias = b1[f0 + w * 64 + nt * 16 + lo];
#pragma unroll
      for (int mt = 0; mt < 4; ++mt)
#pragma unroll
        for (int r = 0; r < 4; ++r) {
          float hv = gelu_tanh(hacc[mt][nt][r] + bias);
          h_lds[(16 * mt + 4 * hi + r) * PSTR + w * 64 + nt * 16 + lo] = f2b(hv);
        }
    }
    __syncthreads();

#pragma unroll
    for (int ks = 0; ks < 256; ks += 32) {
      bfrag8 a[4], b[4];
#pragma unroll
      for (int mt = 0; mt < 4; ++mt)
        a[mt] = *(const bfrag8*)(h_lds + (16 * mt + lo) * PSTR + ks + hi * 8);
#pragma unroll
      for (int nt = 0; nt < 4; ++nt)
        b[nt] = *(const bfrag8*)(u2t + (size_t)(w * 64 + nt * 16 + lo) * D_FF + f0 + ks + hi * 8);
#pragma unroll
      for (int mt = 0; mt < 4; ++mt)
#pragma unroll
        for (int nt = 0; nt < 4; ++nt)
          qacc[mt][nt] = __builtin_amdgcn_mfma_f32_16x16x32_bf16(a[mt], b[nt], qacc[mt][nt], 0, 0, 0);
    }
  }

  float* qp = qpart + (size_t)j * NROWS * RANK;
#pragma unroll
  for (int nt = 0; nt < 4; ++nt) {
    int col = w * 64 + nt * 16 + lo;
#pragma unroll
    for (int mt = 0; mt < 4; ++mt)
#pragma unroll
      for (int r = 0; r < 4; ++r)
        qp[(gr0 + 16 * mt + 4 * hi + r) * RANK + col] = qacc[mt][nt][r];
  }
}

// ---------------- out = (sum_j Qpart_j) @ V2 + b2 : [16384][1024] f32 ----------------
// BM=64, 512 thr (8 waves as 2x4, each 32x64 = 2x4 frags), grid (256, 4).
__global__ __launch_bounds__(512, 4) void ogemm(
    const float* __restrict__ qpart, int fsplit,
    const unsigned short* __restrict__ v2t,   // [D_MODEL][RANK]
    const float* __restrict__ b2,
    float* __restrict__ out)
{
  __shared__ unsigned short Qs[64 * PSTR];
  const int tid = threadIdx.x;
  const int w = tid >> 6, lane = tid & 63, lo = lane & 15, hi = lane >> 4;
  const int wm = w >> 2, wn = w & 3;          // wave grid 2x4
  const size_t gr0 = (size_t)blockIdx.x * 64;
  const int n0 = blockIdx.y * 256;

  // load + reduce partials -> bf16 LDS
#pragma unroll
  for (int it = 0; it < 8; ++it) {
    int idx = it * 512 + tid;
    int r = idx >> 6, c = (idx & 63) << 2;
    fx4 s = *(const fx4*)(qpart + (gr0 + r) * RANK + c);
    if (fsplit == 2) {
      fx4 s1 = *(const fx4*)(qpart + (size_t)NROWS * RANK + (gr0 + r) * RANK + c);
      s[0] += s1[0]; s[1] += s1[1]; s[2] += s1[2]; s[3] += s1[3];
    }
    usx4 bv; bv[0] = f2b(s[0]); bv[1] = f2b(s[1]); bv[2] = f2b(s[2]); bv[3] = f2b(s[3]);
    *(usx4*)(Qs + r * PSTR + c) = bv;
  }
  __syncthreads();

  fx4 acc[2][4];
#pragma unroll
  for (int mt = 0; mt < 2; ++mt)
#pragma unroll
    for (int nt = 0; nt < 4; ++nt) acc[mt][nt] = fx4{0.f, 0.f, 0.f, 0.f};

#pragma unroll
  for (int ks = 0; ks < RANK; ks += 32) {
    bfrag8 a[2], b[4];
#pragma unroll
    for (int mt = 0; mt < 2; ++mt)
      a[mt] = *(const bfrag8*)(Qs + (wm * 32 + 16 * mt + lo) * PSTR + ks + hi * 8);
#pragma unroll
    for (int nt = 0; nt < 4; ++nt)
      b[nt] = *(const bfrag8*)(v2t + (size_t)(n0 + wn * 64 + nt * 16 + lo) * RANK + ks + hi * 8);
#pragma unroll
    for (int mt = 0; mt < 2; ++mt)
#pragma unroll
      for (int nt = 0; nt < 4; ++nt)
        acc[mt][nt] = __builtin_amdgcn_mfma_f32_16x16x32_bf16(a[mt], b[nt], acc[mt][nt], 0, 0, 0);
  }

#pragma unroll
  for (int nt = 0; nt < 4; ++nt) {
    int col = n0 + wn * 64 + nt * 16 + lo;
    float bias = b2[col];
#pragma unroll
    for (int mt = 0; mt < 2; ++mt)
#pragma unroll
      for (int r = 0; r < 4; ++r)
        out[(gr0 + wm * 32 + 16 * mt + 4 * hi + r) * D_MODEL + col] = acc[mt][nt][r] + bias;
  }
}

extern "C" void kernel_launch(void* const* d_in, const int* in_sizes, int n_in,
                              void* d_out, int out_size, void* d_ws, size_t ws_size,
                              hipStream_t stream) {
  const float* x  = (const float*)d_in[0];
  const float* U1 = (const float*)d_in[1];
  const float* V1 = (const float*)d_in[2];
  const float* b1 = (const float*)d_in[3];
  const float* U2 = (const float*)d_in[4];
  const float* V2 = (const float*)d_in[5];
  const float* b2 = (const float*)d_in[6];
  float* out = (float*)d_out;

  unsigned short* ws16 = (unsigned short*)d_ws;
  unsigned short* u1t = ws16;                                 // [256][1024]
  unsigned short* v1t = u1t + (size_t)RANK * D_MODEL;         // [4096][256]
  unsigned short* u2t = v1t + (size_t)D_FF * RANK;            // [256][4096]
  unsigned short* v2t = u2t + (size_t)RANK * D_FF;            // [1024][256]
  unsigned short* Pbf = v2t + (size_t)D_MODEL * RANK;         // [16384][256] bf16
  float* qpart = (float*)(Pbf + (size_t)NROWS * RANK);        // [F][16384][256] f32

  size_t base = (size_t)(5 * 1024 * 1024 + 8 * 1024 * 1024 + 512 * 1024);  // weights+P upper bound
  int fsplit = (ws_size >= base + 2ull * NROWS * RANK * 4) ? 2 : 1;
  int fspan = D_FF / fsplit;

  tconv<<<dim3(RANK / 32, D_MODEL / 32), 256, 0, stream>>>(U1, u1t, D_MODEL, RANK);
  tconv<<<dim3(D_FF / 32, RANK / 32),   256, 0, stream>>>(V1, v1t, RANK, D_FF);
  tconv<<<dim3(RANK / 32, D_FF / 32),   256, 0, stream>>>(U2, u2t, D_FF, RANK);
  tconv<<<dim3(D_MODEL / 32, RANK / 32),256, 0, stream>>>(V2, v2t, RANK, D_MODEL);

  pgemm<<<NROWS / 32, 256, 0, stream>>>(x, u1t, Pbf);
  hqgemm<<<(NROWS / 64) * fsplit, 256, 0, stream>>>(Pbf, v1t, b1, u2t, qpart, fsplit, fspan);
  ogemm<<<dim3(NROWS / 64, D_MODEL / 256), 512, 0, stream>>>(qpart, fsplit, v2t, b2, out);
}